// Round 11
// baseline (413.125 us; speedup 1.0000x reference)
//
#include <hip/hip_runtime.h>
#include <math.h>

// Chamfer distance via EXACT grid nearest-neighbor (fp32, no quantization).
//
// R20 vs R13..R19: five consecutive inner-loop interventions on the MFMA
// brute force (width, occupancy 4->8 w/SIMD, operand path, pure hand-asm)
// were all null at ~28us -- R17/R19 counters show 56% dead-issue cycles that
// no formulation removes. The brute force pays for 268M pairs; Chamfer needs
// 32768 NNs. Switch: uniform grid G=64 over [-6.6,6.6]^3 (h=0.206; inputs
// are N(0,1)^3 so ~9 pts/cell in the core), expanding-ring exact NN:
// after scanning rings 0..r-1, any unscanned point is >= (r-1)*h away
// (q is inside cell cq; a ring-r cell's near face is >= (r-1)*h from q) ->
// break when best^2 <= ((r-1)h)^2. Binning clamps coords into the grid:
// min-safe (clamping moves points inward; true distance >= cell-face bound).
// CSR via concatenated scan of both clouds' counts -> slot indices into ONE
// scat[] array (cloud A slots [0,n1), B [n1,n1+n2)); queries iterate scat[]
// in CELL ORDER so wave lanes are spatially coherent (divergence + cache).
// 7 small dispatches (R17 timestamps: inter-dispatch gap ~0.25us, cheap);
// no grid.sync (R10: ~100us). All fp32 -> absmax should drop 16 -> <0.1.

typedef unsigned int uint;

constexpr int   G    = 64;
constexpr int   G3   = G * G * G;          // 262144 cells per cloud
constexpr float FLO  = -6.6f;
constexpr float FH   = 13.2f / (float)G;   // 0.20625
constexpr float FINVH = (float)G / 13.2f;

// ws layout (4-byte units):
//   counts [2*G3]        @ 0
//   starts [2*G3]        @ 2*G3
//   cursor [2*G3]        @ 4*G3
//   bsums  [512]         @ 6*G3
//   scat   float4[32768] @ 6*G3 + 1024   (byte offset divisible by 16)

__device__ __forceinline__ int cell1(float x) {
    int c = (int)((x - FLO) * FINVH);
    return c < 0 ? 0 : (c > G - 1 ? G - 1 : c);
}

// ---- 1: histogram of cell occupancy (both clouds, concatenated) ----
__global__ __launch_bounds__(256) void hist_kernel(
    const float* __restrict__ P1, const float* __restrict__ P2,
    uint* __restrict__ counts, int n1, int n2)
{
    int i = blockIdx.x * 256 + threadIdx.x;
    const float* P; int base, j;
    if (i < n1)            { P = P1; base = 0;  j = i; }
    else if (i < n1 + n2)  { P = P2; base = G3; j = i - n1; }
    else return;
    float x = P[3*j], y = P[3*j+1], z = P[3*j+2];
    int lin = (cell1(z) * G + cell1(y)) * G + cell1(x);
    atomicAdd(&counts[base + lin], 1u);
}

// ---- 2: block-level exclusive scan (1024/block) ----
__global__ __launch_bounds__(1024) void scan1_kernel(
    const uint* __restrict__ counts, uint* __restrict__ starts,
    uint* __restrict__ bsums)
{
    __shared__ uint s[1024];
    int gid = blockIdx.x * 1024 + threadIdx.x;
    uint v = counts[gid];
    s[threadIdx.x] = v;
    __syncthreads();
#pragma unroll
    for (int d = 1; d < 1024; d <<= 1) {
        uint t = threadIdx.x >= d ? s[threadIdx.x - d] : 0u;
        __syncthreads();
        s[threadIdx.x] += t;
        __syncthreads();
    }
    starts[gid] = s[threadIdx.x] - v;              // exclusive
    if (threadIdx.x == 1023) bsums[blockIdx.x] = s[1023];
}

// ---- 3: scan the 512 block sums (single block) ----
__global__ __launch_bounds__(512) void scan2_kernel(uint* __restrict__ bsums)
{
    __shared__ uint s[512];
    uint v = bsums[threadIdx.x];
    s[threadIdx.x] = v;
    __syncthreads();
#pragma unroll
    for (int d = 1; d < 512; d <<= 1) {
        uint t = threadIdx.x >= d ? s[threadIdx.x - d] : 0u;
        __syncthreads();
        s[threadIdx.x] += t;
        __syncthreads();
    }
    bsums[threadIdx.x] = s[threadIdx.x] - v;       // exclusive
}

// ---- 4: add block offsets; copy to cursor; zero out[0] ----
__global__ __launch_bounds__(1024) void scan3_kernel(
    uint* __restrict__ starts, uint* __restrict__ cursor,
    const uint* __restrict__ bsums, float* __restrict__ out)
{
    int gid = blockIdx.x * 1024 + threadIdx.x;
    uint v = starts[gid] + bsums[blockIdx.x];
    starts[gid] = v;
    cursor[gid] = v;
    if (gid == 0) out[0] = 0.0f;                   // before query's atomics
}

// ---- 5: scatter points into cell-ordered slots ----
__global__ __launch_bounds__(256) void scatter_kernel(
    const float* __restrict__ P1, const float* __restrict__ P2,
    uint* __restrict__ cursor, float4* __restrict__ scat, int n1, int n2)
{
    int i = blockIdx.x * 256 + threadIdx.x;
    const float* P; int base, j;
    if (i < n1)            { P = P1; base = 0;  j = i; }
    else if (i < n1 + n2)  { P = P2; base = G3; j = i - n1; }
    else return;
    float x = P[3*j], y = P[3*j+1], z = P[3*j+2];
    int lin = (cell1(z) * G + cell1(y)) * G + cell1(x);
    uint pos = atomicAdd(&cursor[base + lin], 1u);
    scat[pos] = make_float4(x, y, z, 0.0f);
}

// scan one contiguous x-run of cells [x0..x1] in row (rowBase = (z*G+y)*G)
__device__ __forceinline__ void span(
    const uint* __restrict__ starts, const float4* __restrict__ scat,
    int cellBase, int nTot, float4 q, float& best, int rowBase, int x0, int x1)
{
    int gi0 = cellBase + rowBase + x0;
    int gi1 = cellBase + rowBase + x1 + 1;
    uint s = starts[gi0];
    uint e = (gi1 < 2 * G3) ? starts[gi1] : (uint)nTot;
    for (uint k = s; k < e; ++k) {
        float4 p = scat[k];
        float dx = q.x - p.x, dy = q.y - p.y, dz = q.z - p.z;
        best = fminf(best, dx*dx + dy*dy + dz*dz);
    }
}

// ---- 6: exact NN query per scattered point (cell-ordered => coherent waves)
//         + block sum + one atomicAdd ----
__global__ __launch_bounds__(128) void query_kernel(
    const uint* __restrict__ starts, const float4* __restrict__ scat,
    float* __restrict__ out, int n1, int n2)
{
    int i = blockIdx.x * 128 + threadIdx.x;
    const int nTot = n1 + n2;
    float acc = 0.0f;
    if (i < nTot) {
        float4 q = scat[i];
        const int cellBase = (i < n1) ? G3 : 0;    // search the OTHER cloud
        int cx = cell1(q.x), cy = cell1(q.y), cz = cell1(q.z);
        float best = 1e30f;

        span(starts, scat, cellBase, nTot, q, best, (cz * G + cy) * G, cx, cx);

        for (int r = 1; r < G; ++r) {
            float bd = (float)(r - 1) * FH;        // unscanned >= (r-1)*h away
            if (best <= bd * bd) break;
            int x0 = cx - r < 0 ? 0 : cx - r,  x1 = cx + r > G-1 ? G-1 : cx + r;
            int y0 = cy - r < 0 ? 0 : cy - r,  y1 = cy + r > G-1 ? G-1 : cy + r;
            // z faces (full x-range rows)
            if (cz - r >= 0) { int zb = (cz - r) * G;
                for (int y = y0; y <= y1; ++y) span(starts, scat, cellBase, nTot, q, best, (zb + y) * G, x0, x1); }
            if (cz + r < G)  { int zb = (cz + r) * G;
                for (int y = y0; y <= y1; ++y) span(starts, scat, cellBase, nTot, q, best, (zb + y) * G, x0, x1); }
            // y faces (z interior) and x faces (z,y interior)
            int zi0 = cz - r + 1 < 0 ? 0 : cz - r + 1,  zi1 = cz + r - 1 > G-1 ? G-1 : cz + r - 1;
            int yi0 = cy - r + 1 < 0 ? 0 : cy - r + 1,  yi1 = cy + r - 1 > G-1 ? G-1 : cy + r - 1;
            for (int z = zi0; z <= zi1; ++z) {
                int zb = z * G;
                if (cy - r >= 0) span(starts, scat, cellBase, nTot, q, best, (zb + cy - r) * G, x0, x1);
                if (cy + r < G)  span(starts, scat, cellBase, nTot, q, best, (zb + cy + r) * G, x0, x1);
                for (int y = yi0; y <= yi1; ++y) {
                    if (cx - r >= 0) span(starts, scat, cellBase, nTot, q, best, (zb + y) * G, cx - r, cx - r);
                    if (cx + r < G)  span(starts, scat, cellBase, nTot, q, best, (zb + y) * G, cx + r, cx + r);
                }
            }
        }
        acc = sqrtf(best);                          // exact d^2 >= 0
    }

    __shared__ float red[2];
#pragma unroll
    for (int m = 1; m <= 32; m <<= 1) acc += __shfl_xor(acc, m);
    if ((threadIdx.x & 63) == 0) red[threadIdx.x >> 6] = acc;
    __syncthreads();
    if (threadIdx.x == 0) atomicAdd(out, red[0] + red[1]);
}

extern "C" void kernel_launch(void* const* d_in, const int* in_sizes, int n_in,
                              void* d_out, int out_size, void* d_ws, size_t ws_size,
                              hipStream_t stream) {
    const float* P1 = (const float*)d_in[0];
    const float* P2 = (const float*)d_in[1];
    const int n1 = in_sizes[0] / 3;   // 16384
    const int n2 = in_sizes[1] / 3;   // 16384
    const int nTot = n1 + n2;

    uint*   counts = (uint*)d_ws;
    uint*   starts = counts + 2 * G3;
    uint*   cursor = starts + 2 * G3;
    uint*   bsums  = cursor + 2 * G3;
    float4* scat   = (float4*)(bsums + 1024);     // 16B-aligned by layout
    float*  out    = (float*)d_out;

    hipMemsetAsync(counts, 0, 2 * G3 * sizeof(uint), stream);

    hist_kernel   <<<(nTot + 255) / 256, 256, 0, stream>>>(P1, P2, counts, n1, n2);
    scan1_kernel  <<<2 * G3 / 1024, 1024, 0, stream>>>(counts, starts, bsums);
    scan2_kernel  <<<1, 512, 0, stream>>>(bsums);
    scan3_kernel  <<<2 * G3 / 1024, 1024, 0, stream>>>(starts, cursor, bsums, out);
    scatter_kernel<<<(nTot + 255) / 256, 256, 0, stream>>>(P1, P2, cursor, scat, n1, n2);
    query_kernel  <<<(nTot + 127) / 128, 128, 0, stream>>>(starts, scat, out, n1, n2);
}

// Round 12
// 232.467 us; speedup vs baseline: 1.7771x; 1.7771x over previous
//
#include <hip/hip_runtime.h>
#include <math.h>

// Chamfer distance via EXACT grid nearest-neighbor (fp32, no quantization).
//
// R21 vs R20: R20 validated the algorithm (absmax 0.0) but query ran 332us
// at Occupancy 0.78% / VALUBusy 1.1% -- one lane per query = 512 waves on
// 1024 SIMDs, serial dependent L2 loads, nothing hides latency. Fix:
// 16 cooperative lanes per query (shfl_xor-reduced best within each
// 16-lane group) -> 8192 waves = 32/CU (HW max), 16x less serial work per
// lane. Ring-r shells (24r^2+2 cells) are enumerated by a linear index ->
// (dz,dy,dx) map and distributed over the 16 lanes too; scat[] is
// cell-ordered so outlier queries cluster into few waves. Scan kernels
// rewritten as wave-shuffle scans (3 barriers instead of 20).
// Algorithm (proven R20): uniform grid G=64 over [-6.6,6.6]^3; CSR via
// concatenated scan of both clouds' counts; expanding-ring exact NN with
// bound "after scanning Chebyshev rings 0..r-1, unscanned points are
// >= (r-1)*h away"; clamped binning is min-safe. 7 dispatches, no grid.sync.

typedef unsigned int uint;

constexpr int   G    = 64;
constexpr int   G3   = G * G * G;          // 262144 cells per cloud
constexpr float FLO  = -6.6f;
constexpr float FH   = 13.2f / (float)G;   // 0.20625
constexpr float FINVH = (float)G / 13.2f;

__device__ __forceinline__ int cell1(float x) {
    int c = (int)((x - FLO) * FINVH);
    return c < 0 ? 0 : (c > G - 1 ? G - 1 : c);
}

// ---- 1: histogram of cell occupancy (both clouds, concatenated) ----
__global__ __launch_bounds__(256) void hist_kernel(
    const float* __restrict__ P1, const float* __restrict__ P2,
    uint* __restrict__ counts, int n1, int n2)
{
    int i = blockIdx.x * 256 + threadIdx.x;
    const float* P; int base, j;
    if (i < n1)            { P = P1; base = 0;  j = i; }
    else if (i < n1 + n2)  { P = P2; base = G3; j = i - n1; }
    else return;
    float x = P[3*j], y = P[3*j+1], z = P[3*j+2];
    int lin = (cell1(z) * G + cell1(y)) * G + cell1(x);
    atomicAdd(&counts[base + lin], 1u);
}

// ---- 2: block exclusive scan, wave-shuffle (1024 thr = 16 waves) ----
__global__ __launch_bounds__(1024) void scan1_kernel(
    const uint* __restrict__ counts, uint* __restrict__ starts,
    uint* __restrict__ bsums)
{
    __shared__ uint ws[16];
    int gid = blockIdx.x * 1024 + threadIdx.x;
    int lane = threadIdx.x & 63, w = threadIdx.x >> 6;
    uint v = counts[gid];
    uint x = v;                                   // inclusive wave scan
#pragma unroll
    for (int d = 1; d < 64; d <<= 1) { uint t = __shfl_up(x, d); if (lane >= d) x += t; }
    if (lane == 63) ws[w] = x;
    __syncthreads();
    if (w == 0) {
        uint y = (lane < 16) ? ws[lane] : 0u;
#pragma unroll
        for (int d = 1; d < 16; d <<= 1) { uint t = __shfl_up(y, d); if (lane >= d) y += t; }
        if (lane < 16) ws[lane] = y;
    }
    __syncthreads();
    uint add = (w > 0) ? ws[w - 1] : 0u;
    starts[gid] = add + x - v;                    // exclusive
    if (threadIdx.x == 1023) bsums[blockIdx.x] = add + x;
}

// ---- 3: scan the 512 block sums (single block, 8 waves) ----
__global__ __launch_bounds__(512) void scan2_kernel(uint* __restrict__ bsums)
{
    __shared__ uint ws[8];
    int lane = threadIdx.x & 63, w = threadIdx.x >> 6;
    uint v = bsums[threadIdx.x];
    uint x = v;
#pragma unroll
    for (int d = 1; d < 64; d <<= 1) { uint t = __shfl_up(x, d); if (lane >= d) x += t; }
    if (lane == 63) ws[w] = x;
    __syncthreads();
    if (w == 0) {
        uint y = (lane < 8) ? ws[lane] : 0u;
#pragma unroll
        for (int d = 1; d < 8; d <<= 1) { uint t = __shfl_up(y, d); if (lane >= d) y += t; }
        if (lane < 8) ws[lane] = y;
    }
    __syncthreads();
    uint add = (w > 0) ? ws[w - 1] : 0u;
    bsums[threadIdx.x] = add + x - v;             // exclusive
}

// ---- 4: add block offsets; copy to cursor; zero out[0] ----
__global__ __launch_bounds__(1024) void scan3_kernel(
    uint* __restrict__ starts, uint* __restrict__ cursor,
    const uint* __restrict__ bsums, float* __restrict__ out)
{
    int gid = blockIdx.x * 1024 + threadIdx.x;
    uint v = starts[gid] + bsums[blockIdx.x];
    starts[gid] = v;
    cursor[gid] = v;
    if (gid == 0) out[0] = 0.0f;                  // before query's atomics
}

// ---- 5: scatter points into cell-ordered slots ----
__global__ __launch_bounds__(256) void scatter_kernel(
    const float* __restrict__ P1, const float* __restrict__ P2,
    uint* __restrict__ cursor, float4* __restrict__ scat, int n1, int n2)
{
    int i = blockIdx.x * 256 + threadIdx.x;
    const float* P; int base, j;
    if (i < n1)            { P = P1; base = 0;  j = i; }
    else if (i < n1 + n2)  { P = P2; base = G3; j = i - n1; }
    else return;
    float x = P[3*j], y = P[3*j+1], z = P[3*j+2];
    int lin = (cell1(z) * G + cell1(y)) * G + cell1(x);
    uint pos = atomicAdd(&cursor[base + lin], 1u);
    scat[pos] = make_float4(x, y, z, 0.0f);
}

// scan one cell's points against q
__device__ __forceinline__ void scan_cell(
    const uint* __restrict__ starts, const float4* __restrict__ scat,
    int gi, int nTot, float4 q, float& best)
{
    uint s = starts[gi];
    uint e = (gi + 1 < 2 * G3) ? starts[gi + 1] : (uint)nTot;
    for (uint k = s; k < e; ++k) {
        float4 p = scat[k];
        float dx = q.x - p.x, dy = q.y - p.y, dz = q.z - p.z;
        best = fminf(best, dx*dx + dy*dy + dz*dz);
    }
}

// ---- 6: exact NN query, 16 cooperative lanes per query ----
__global__ __launch_bounds__(256) void query_kernel(
    const uint* __restrict__ starts, const float4* __restrict__ scat,
    float* __restrict__ out, int n1, int n2)
{
    const int nTot = n1 + n2;
    const int sub  = threadIdx.x & 15;
    const int i    = blockIdx.x * 16 + (threadIdx.x >> 4);

    float acc = 0.0f;
    if (i < nTot) {
        float4 q = scat[i];                        // broadcast within group
        const int cellBase = (i < n1) ? G3 : 0;    // search the OTHER cloud
        int cx = cell1(q.x), cy = cell1(q.y), cz = cell1(q.z);
        float best = 1e30f;

        // phase A: 3x3x3 box (27 cells) split across 16 lanes
        for (int idx = sub; idx < 27; idx += 16) {
            int dz = idx / 9 - 1, rem = idx % 9;
            int dy = rem / 3 - 1, dx = rem % 3 - 1;
            int x = cx + dx, y = cy + dy, z = cz + dz;
            if ((uint)x >= G || (uint)y >= G || (uint)z >= G) continue;
            scan_cell(starts, scat, cellBase + (z * G + y) * G + x, nTot, q, best);
        }
#pragma unroll
        for (int m = 1; m <= 8; m <<= 1) best = fminf(best, __shfl_xor(best, m, 16));

        // phase B: expanding Chebyshev rings (rare; outliers cluster in waves)
        if (best > FH * FH) {
            for (int r = 2; r < G; ++r) {
                float bd = (float)(r - 1) * FH;    // unscanned >= (r-1)*h away
                if (best <= bd * bd) break;
                const int S = 2 * r + 1, I = 2 * r - 1;
                const int nf = 2 * S * S, ne = 2 * I * S;
                const int nc = 24 * r * r + 2;
                for (int idx = sub; idx < nc; idx += 16) {
                    int dz, dy, dx, t = idx;
                    if (t < nf) {
                        int f = t / (S * S); int rem = t - f * S * S;
                        dz = f ? r : -r; dy = rem / S - r; dx = rem - (rem / S) * S - r;
                    } else {
                        t -= nf;
                        if (t < ne) {
                            int f = t / (I * S); int rem = t - f * I * S;
                            dy = f ? r : -r; dz = rem / S - (r - 1); dx = rem - (rem / S) * S - r;
                        } else {
                            t -= ne;
                            int f = t / (I * I); int rem = t - f * I * I;
                            dx = f ? r : -r; dz = rem / I - (r - 1); dy = rem - (rem / I) * I - (r - 1);
                        }
                    }
                    int x = cx + dx, y = cy + dy, z = cz + dz;
                    if ((uint)x >= G || (uint)y >= G || (uint)z >= G) continue;
                    scan_cell(starts, scat, cellBase + (z * G + y) * G + x, nTot, q, best);
                }
#pragma unroll
                for (int m = 1; m <= 8; m <<= 1) best = fminf(best, __shfl_xor(best, m, 16));
            }
        }
        if (sub == 0) acc = sqrtf(best);           // exact d^2 >= 0
    }

    // block sum: sub==0 lanes live at wave lanes 0,16,32,48
#pragma unroll
    for (int m = 16; m <= 32; m <<= 1) acc += __shfl_xor(acc, m);
    __shared__ float red[4];
    if ((threadIdx.x & 63) == 0) red[threadIdx.x >> 6] = acc;
    __syncthreads();
    if (threadIdx.x == 0) atomicAdd(out, red[0] + red[1] + red[2] + red[3]);
}

extern "C" void kernel_launch(void* const* d_in, const int* in_sizes, int n_in,
                              void* d_out, int out_size, void* d_ws, size_t ws_size,
                              hipStream_t stream) {
    const float* P1 = (const float*)d_in[0];
    const float* P2 = (const float*)d_in[1];
    const int n1 = in_sizes[0] / 3;   // 16384
    const int n2 = in_sizes[1] / 3;   // 16384
    const int nTot = n1 + n2;

    uint*   counts = (uint*)d_ws;
    uint*   starts = counts + 2 * G3;
    uint*   cursor = starts + 2 * G3;
    uint*   bsums  = cursor + 2 * G3;
    float4* scat   = (float4*)(bsums + 1024);     // 16B-aligned by layout
    float*  out    = (float*)d_out;

    hipMemsetAsync(counts, 0, 2 * G3 * sizeof(uint), stream);

    hist_kernel   <<<(nTot + 255) / 256, 256, 0, stream>>>(P1, P2, counts, n1, n2);
    scan1_kernel  <<<2 * G3 / 1024, 1024, 0, stream>>>(counts, starts, bsums);
    scan2_kernel  <<<1, 512, 0, stream>>>(bsums);
    scan3_kernel  <<<2 * G3 / 1024, 1024, 0, stream>>>(starts, cursor, bsums, out);
    scatter_kernel<<<(nTot + 255) / 256, 256, 0, stream>>>(P1, P2, cursor, scat, n1, n2);
    query_kernel  <<<(nTot + 15) / 16, 256, 0, stream>>>(starts, scat, out, n1, n2);
}

// Round 13
// 119.210 us; speedup vs baseline: 3.4655x; 1.9501x over previous
//
#include <hip/hip_runtime.h>
#include <math.h>

// Chamfer distance via EXACT grid nearest-neighbor (fp32, no quantization).
//
// R22 vs R21: R21 cut query 332->165us but counters (Occ 9.7%, VALU 4.3%)
// show a pure outlier TAIL: ~500 sparse-region queries need rings r=4..9
// (Sum 24r^2 / 16 lanes ~ 425 serial cells/lane, ~200cyc dependent loads
// each), and cell-ordering clusters them into a few waves that run alone.
// Fix: cap kernel A's rings at r<=3 (exact: after rings 0..3 unscanned
// points are >= 3h away -> converged iff best <= (3h)^2; expected
// unconverged ~ P(NN>0.62) ~ 0.3% ~ 100-500 queries -> worklist). Kernel B
// brute-forces each worklist query against the other cloud's WHOLE scat
// range (256KB, L2-resident) with one 256-thread block per item: pure
// streaming, no dependent chains, no tail. wlcount zeroed in scan3.
// Algorithm core (proven R20/R21, absmax 0.0): grid G=64 over [-6.6,6.6]^3,
// CSR via concatenated shuffle-scans, clamped binning min-safe, expanding-
// ring bound exact. 8 dispatches, no grid.sync.

typedef unsigned int uint;

constexpr int   G    = 64;
constexpr int   G3   = G * G * G;          // 262144 cells per cloud
constexpr float FLO  = -6.6f;
constexpr float FH   = 13.2f / (float)G;   // 0.20625
constexpr float FINVH = (float)G / 13.2f;

__device__ __forceinline__ int cell1(float x) {
    int c = (int)((x - FLO) * FINVH);
    return c < 0 ? 0 : (c > G - 1 ? G - 1 : c);
}

// ---- 1: histogram of cell occupancy (both clouds, concatenated) ----
__global__ __launch_bounds__(256) void hist_kernel(
    const float* __restrict__ P1, const float* __restrict__ P2,
    uint* __restrict__ counts, int n1, int n2)
{
    int i = blockIdx.x * 256 + threadIdx.x;
    const float* P; int base, j;
    if (i < n1)            { P = P1; base = 0;  j = i; }
    else if (i < n1 + n2)  { P = P2; base = G3; j = i - n1; }
    else return;
    float x = P[3*j], y = P[3*j+1], z = P[3*j+2];
    int lin = (cell1(z) * G + cell1(y)) * G + cell1(x);
    atomicAdd(&counts[base + lin], 1u);
}

// ---- 2: block exclusive scan, wave-shuffle (1024 thr = 16 waves) ----
__global__ __launch_bounds__(1024) void scan1_kernel(
    const uint* __restrict__ counts, uint* __restrict__ starts,
    uint* __restrict__ bsums)
{
    __shared__ uint ws[16];
    int gid = blockIdx.x * 1024 + threadIdx.x;
    int lane = threadIdx.x & 63, w = threadIdx.x >> 6;
    uint v = counts[gid];
    uint x = v;                                   // inclusive wave scan
#pragma unroll
    for (int d = 1; d < 64; d <<= 1) { uint t = __shfl_up(x, d); if (lane >= d) x += t; }
    if (lane == 63) ws[w] = x;
    __syncthreads();
    if (w == 0) {
        uint y = (lane < 16) ? ws[lane] : 0u;
#pragma unroll
        for (int d = 1; d < 16; d <<= 1) { uint t = __shfl_up(y, d); if (lane >= d) y += t; }
        if (lane < 16) ws[lane] = y;
    }
    __syncthreads();
    uint add = (w > 0) ? ws[w - 1] : 0u;
    starts[gid] = add + x - v;                    // exclusive
    if (threadIdx.x == 1023) bsums[blockIdx.x] = add + x;
}

// ---- 3: scan the 512 block sums (single block, 8 waves) ----
__global__ __launch_bounds__(512) void scan2_kernel(uint* __restrict__ bsums)
{
    __shared__ uint ws[8];
    int lane = threadIdx.x & 63, w = threadIdx.x >> 6;
    uint v = bsums[threadIdx.x];
    uint x = v;
#pragma unroll
    for (int d = 1; d < 64; d <<= 1) { uint t = __shfl_up(x, d); if (lane >= d) x += t; }
    if (lane == 63) ws[w] = x;
    __syncthreads();
    if (w == 0) {
        uint y = (lane < 8) ? ws[lane] : 0u;
#pragma unroll
        for (int d = 1; d < 8; d <<= 1) { uint t = __shfl_up(y, d); if (lane >= d) y += t; }
        if (lane < 8) ws[lane] = y;
    }
    __syncthreads();
    uint add = (w > 0) ? ws[w - 1] : 0u;
    bsums[threadIdx.x] = add + x - v;             // exclusive
}

// ---- 4: add block offsets; copy to cursor; zero out[0] + wlcount ----
__global__ __launch_bounds__(1024) void scan3_kernel(
    uint* __restrict__ starts, uint* __restrict__ cursor,
    const uint* __restrict__ bsums, float* __restrict__ out,
    uint* __restrict__ wlcount)
{
    int gid = blockIdx.x * 1024 + threadIdx.x;
    uint v = starts[gid] + bsums[blockIdx.x];
    starts[gid] = v;
    cursor[gid] = v;
    if (gid == 0) { out[0] = 0.0f; wlcount[0] = 0u; }   // before query atomics
}

// ---- 5: scatter points into cell-ordered slots ----
__global__ __launch_bounds__(256) void scatter_kernel(
    const float* __restrict__ P1, const float* __restrict__ P2,
    uint* __restrict__ cursor, float4* __restrict__ scat, int n1, int n2)
{
    int i = blockIdx.x * 256 + threadIdx.x;
    const float* P; int base, j;
    if (i < n1)            { P = P1; base = 0;  j = i; }
    else if (i < n1 + n2)  { P = P2; base = G3; j = i - n1; }
    else return;
    float x = P[3*j], y = P[3*j+1], z = P[3*j+2];
    int lin = (cell1(z) * G + cell1(y)) * G + cell1(x);
    uint pos = atomicAdd(&cursor[base + lin], 1u);
    scat[pos] = make_float4(x, y, z, 0.0f);
}

// scan one cell's points against q
__device__ __forceinline__ void scan_cell(
    const uint* __restrict__ starts, const float4* __restrict__ scat,
    int gi, int nTot, float4 q, float& best)
{
    uint s = starts[gi];
    uint e = (gi + 1 < 2 * G3) ? starts[gi + 1] : (uint)nTot;
    for (uint k = s; k < e; ++k) {
        float4 p = scat[k];
        float dx = q.x - p.x, dy = q.y - p.y, dz = q.z - p.z;
        best = fminf(best, dx*dx + dy*dy + dz*dz);
    }
}

// ---- 6: NN query, 16 lanes/query, rings capped at r<=3; stragglers -> wl ----
__global__ __launch_bounds__(256) void query_kernel(
    const uint* __restrict__ starts, const float4* __restrict__ scat,
    float* __restrict__ out, uint* __restrict__ wl, uint* __restrict__ wlcount,
    int n1, int n2)
{
    const int nTot = n1 + n2;
    const int sub  = threadIdx.x & 15;
    const int i    = blockIdx.x * 16 + (threadIdx.x >> 4);

    float acc = 0.0f;
    if (i < nTot) {
        float4 q = scat[i];                        // broadcast within group
        const int cellBase = (i < n1) ? G3 : 0;    // search the OTHER cloud
        int cx = cell1(q.x), cy = cell1(q.y), cz = cell1(q.z);
        float best = 1e30f;

        // phase A: 3x3x3 box (27 cells = rings 0..1) split across 16 lanes
        for (int idx = sub; idx < 27; idx += 16) {
            int dz = idx / 9 - 1, rem = idx % 9;
            int dy = rem / 3 - 1, dx = rem % 3 - 1;
            int x = cx + dx, y = cy + dy, z = cz + dz;
            if ((uint)x >= G || (uint)y >= G || (uint)z >= G) continue;
            scan_cell(starts, scat, cellBase + (z * G + y) * G + x, nTot, q, best);
        }
#pragma unroll
        for (int m = 1; m <= 8; m <<= 1) best = fminf(best, __shfl_xor(best, m, 16));

        // phase B: rings 2..3 only (tail goes to the brute-force worklist)
        if (best > FH * FH) {
            for (int r = 2; r <= 3; ++r) {
                float bd = (float)(r - 1) * FH;    // unscanned >= (r-1)*h away
                if (best <= bd * bd) break;
                const int S = 2 * r + 1, I = 2 * r - 1;
                const int nf = 2 * S * S, ne = 2 * I * S;
                const int nc = 24 * r * r + 2;
                for (int idx = sub; idx < nc; idx += 16) {
                    int dz, dy, dx, t = idx;
                    if (t < nf) {
                        int f = t / (S * S); int rem = t - f * S * S;
                        dz = f ? r : -r; dy = rem / S - r; dx = rem - (rem / S) * S - r;
                    } else {
                        t -= nf;
                        if (t < ne) {
                            int f = t / (I * S); int rem = t - f * I * S;
                            dy = f ? r : -r; dz = rem / S - (r - 1); dx = rem - (rem / S) * S - r;
                        } else {
                            t -= ne;
                            int f = t / (I * I); int rem = t - f * I * I;
                            dx = f ? r : -r; dz = rem / I - (r - 1); dy = rem - (rem / I) * I - (r - 1);
                        }
                    }
                    int x = cx + dx, y = cy + dy, z = cz + dz;
                    if ((uint)x >= G || (uint)y >= G || (uint)z >= G) continue;
                    scan_cell(starts, scat, cellBase + (z * G + y) * G + x, nTot, q, best);
                }
#pragma unroll
                for (int m = 1; m <= 8; m <<= 1) best = fminf(best, __shfl_xor(best, m, 16));
            }
        }

        // exact iff best <= (3h)^2 (rings 0..3 scanned); else brute-force later
        if (best <= 9.0f * FH * FH) {
            if (sub == 0) acc = sqrtf(best);
        } else {
            if (sub == 0) { uint pos = atomicAdd(wlcount, 1u); wl[pos] = (uint)i; }
        }
    }

    // block sum of converged results: sub==0 lanes at wave lanes 0,16,32,48
#pragma unroll
    for (int m = 16; m <= 32; m <<= 1) acc += __shfl_xor(acc, m);
    __shared__ float red[4];
    if ((threadIdx.x & 63) == 0) red[threadIdx.x >> 6] = acc;
    __syncthreads();
    if (threadIdx.x == 0) atomicAdd(out, red[0] + red[1] + red[2] + red[3]);
}

// ---- 7: brute-force the worklist: one block per query, streaming L2 ----
__global__ __launch_bounds__(256) void brute_kernel(
    const float4* __restrict__ scat, const uint* __restrict__ wl,
    const uint* __restrict__ wlcount, float* __restrict__ out, int n1, int n2)
{
    __shared__ float red[4];
    const int nTot = n1 + n2;
    const uint cnt = wlcount[0];
    for (uint w = blockIdx.x; w < cnt; w += gridDim.x) {
        uint qi = wl[w];
        float4 q = scat[qi];
        int ob = (qi < (uint)n1) ? n1 : 0;         // other cloud's scat range
        int oe = (qi < (uint)n1) ? nTot : n1;
        float best = 1e30f;
        for (int j = ob + threadIdx.x; j < oe; j += 256) {
            float4 p = scat[j];
            float dx = q.x - p.x, dy = q.y - p.y, dz = q.z - p.z;
            best = fminf(best, dx*dx + dy*dy + dz*dz);
        }
#pragma unroll
        for (int m = 1; m <= 32; m <<= 1) best = fminf(best, __shfl_xor(best, m));
        if ((threadIdx.x & 63) == 0) red[threadIdx.x >> 6] = best;
        __syncthreads();
        if (threadIdx.x == 0) {
            float b = fminf(fminf(red[0], red[1]), fminf(red[2], red[3]));
            atomicAdd(out, sqrtf(b));
        }
        __syncthreads();                           // red reused next item
    }
}

extern "C" void kernel_launch(void* const* d_in, const int* in_sizes, int n_in,
                              void* d_out, int out_size, void* d_ws, size_t ws_size,
                              hipStream_t stream) {
    const float* P1 = (const float*)d_in[0];
    const float* P2 = (const float*)d_in[1];
    const int n1 = in_sizes[0] / 3;   // 16384
    const int n2 = in_sizes[1] / 3;   // 16384
    const int nTot = n1 + n2;

    uint*   counts  = (uint*)d_ws;
    uint*   starts  = counts + 2 * G3;
    uint*   cursor  = starts + 2 * G3;
    uint*   bsums   = cursor + 2 * G3;
    float4* scat    = (float4*)(bsums + 1024);    // 16B-aligned by layout
    uint*   wl      = (uint*)(scat + 32768);
    uint*   wlcount = wl + 32768;
    float*  out     = (float*)d_out;

    hipMemsetAsync(counts, 0, 2 * G3 * sizeof(uint), stream);

    hist_kernel   <<<(nTot + 255) / 256, 256, 0, stream>>>(P1, P2, counts, n1, n2);
    scan1_kernel  <<<2 * G3 / 1024, 1024, 0, stream>>>(counts, starts, bsums);
    scan2_kernel  <<<1, 512, 0, stream>>>(bsums);
    scan3_kernel  <<<2 * G3 / 1024, 1024, 0, stream>>>(starts, cursor, bsums, out, wlcount);
    scatter_kernel<<<(nTot + 255) / 256, 256, 0, stream>>>(P1, P2, cursor, scat, n1, n2);
    query_kernel  <<<(nTot + 15) / 16, 256, 0, stream>>>(starts, scat, out, wl, wlcount, n1, n2);
    brute_kernel  <<<1024, 256, 0, stream>>>(scat, wl, wlcount, out, n1, n2);
}

// Round 14
// 118.922 us; speedup vs baseline: 3.4739x; 1.0024x over previous
//
#include <hip/hip_runtime.h>
#include <math.h>

// Chamfer distance via EXACT grid nearest-neighbor (fp32, no quantization).
//
// R23 vs R22: R22 counters: query 39.6us (Occ 32%, VALU 14% -> still
// scattered-dependent-load + divergence bound) and ~20us unaccounted =
// brute with cnt~2500 (P(NN>0.62)=7.6%, measured -- density model was 10x
// off). Two fixes: (1) G 64->48 (h=0.275): worklist threshold 3h=0.825 ->
// cnt ~300-800 (exp(-lambda t^3) scaling from the measured anchor), brute
// ~4us; cell bookkeeping shrinks 2.4x. (2) block-shared staged query: 16
// consecutive queries (cell-ordered => same neighborhood) stage the UNION
// of their 3x3x3 boxes into LDS (SoA) via contiguous CSR row-spans --
// coalesced independent loads, 16x less L2 traffic, divergence-free eval;
// block-uniform fallback to the proven R22 per-query path when the union
// is too spread (sparse blocks). Rings 2..3 + worklist + brute unchanged;
// exactness bound unchanged (after rings 0..3: unscanned >= 3h away;
// clamped binning min-safe -- proven R20, absmax 0.0).

typedef unsigned int uint;

constexpr int   G    = 48;
constexpr int   G3   = G * G * G;          // 110592 cells per cloud
constexpr float FLO  = -6.6f;
constexpr float FH   = 13.2f / (float)G;   // 0.275
constexpr float FINVH = (float)G / 13.2f;

constexpr int CAP   = 1536;                // staged candidate cap (SoA 18 KB)
constexpr int NRMAX = 64;                  // staged row cap (one wave scans it)

__device__ __forceinline__ int cell1(float x) {
    int c = (int)((x - FLO) * FINVH);
    return c < 0 ? 0 : (c > G - 1 ? G - 1 : c);
}

// ---- 1: histogram of cell occupancy (both clouds, concatenated) ----
__global__ __launch_bounds__(256) void hist_kernel(
    const float* __restrict__ P1, const float* __restrict__ P2,
    uint* __restrict__ counts, int n1, int n2)
{
    int i = blockIdx.x * 256 + threadIdx.x;
    const float* P; int base, j;
    if (i < n1)            { P = P1; base = 0;  j = i; }
    else if (i < n1 + n2)  { P = P2; base = G3; j = i - n1; }
    else return;
    float x = P[3*j], y = P[3*j+1], z = P[3*j+2];
    int lin = (cell1(z) * G + cell1(y)) * G + cell1(x);
    atomicAdd(&counts[base + lin], 1u);
}

// ---- 2: block exclusive scan, wave-shuffle (1024 thr = 16 waves) ----
__global__ __launch_bounds__(1024) void scan1_kernel(
    const uint* __restrict__ counts, uint* __restrict__ starts,
    uint* __restrict__ bsums)
{
    __shared__ uint ws[16];
    int gid = blockIdx.x * 1024 + threadIdx.x;
    int lane = threadIdx.x & 63, w = threadIdx.x >> 6;
    uint v = counts[gid];
    uint x = v;                                   // inclusive wave scan
#pragma unroll
    for (int d = 1; d < 64; d <<= 1) { uint t = __shfl_up(x, d); if (lane >= d) x += t; }
    if (lane == 63) ws[w] = x;
    __syncthreads();
    if (w == 0) {
        uint y = (lane < 16) ? ws[lane] : 0u;
#pragma unroll
        for (int d = 1; d < 16; d <<= 1) { uint t = __shfl_up(y, d); if (lane >= d) y += t; }
        if (lane < 16) ws[lane] = y;
    }
    __syncthreads();
    uint add = (w > 0) ? ws[w - 1] : 0u;
    starts[gid] = add + x - v;                    // exclusive
    if (threadIdx.x == 1023) bsums[blockIdx.x] = add + x;
}

// ---- 3: scan the 216 block sums (single block, 4 waves) ----
__global__ __launch_bounds__(256) void scan2_kernel(uint* __restrict__ bsums, int nb)
{
    __shared__ uint ws[4];
    int lane = threadIdx.x & 63, w = threadIdx.x >> 6;
    uint v = (threadIdx.x < nb) ? bsums[threadIdx.x] : 0u;
    uint x = v;
#pragma unroll
    for (int d = 1; d < 64; d <<= 1) { uint t = __shfl_up(x, d); if (lane >= d) x += t; }
    if (lane == 63) ws[w] = x;
    __syncthreads();
    if (w == 0) {
        uint y = (lane < 4) ? ws[lane] : 0u;
#pragma unroll
        for (int d = 1; d < 4; d <<= 1) { uint t = __shfl_up(y, d); if (lane >= d) y += t; }
        if (lane < 4) ws[lane] = y;
    }
    __syncthreads();
    uint add = (w > 0) ? ws[w - 1] : 0u;
    if (threadIdx.x < nb) bsums[threadIdx.x] = add + x - v;   // exclusive
}

// ---- 4: add block offsets; copy to cursor; zero out[0] + wlcount ----
__global__ __launch_bounds__(1024) void scan3_kernel(
    uint* __restrict__ starts, uint* __restrict__ cursor,
    const uint* __restrict__ bsums, float* __restrict__ out,
    uint* __restrict__ wlcount)
{
    int gid = blockIdx.x * 1024 + threadIdx.x;
    uint v = starts[gid] + bsums[blockIdx.x];
    starts[gid] = v;
    cursor[gid] = v;
    if (gid == 0) { out[0] = 0.0f; wlcount[0] = 0u; }   // before query atomics
}

// ---- 5: scatter points into cell-ordered slots ----
__global__ __launch_bounds__(256) void scatter_kernel(
    const float* __restrict__ P1, const float* __restrict__ P2,
    uint* __restrict__ cursor, float4* __restrict__ scat, int n1, int n2)
{
    int i = blockIdx.x * 256 + threadIdx.x;
    const float* P; int base, j;
    if (i < n1)            { P = P1; base = 0;  j = i; }
    else if (i < n1 + n2)  { P = P2; base = G3; j = i - n1; }
    else return;
    float x = P[3*j], y = P[3*j+1], z = P[3*j+2];
    int lin = (cell1(z) * G + cell1(y)) * G + cell1(x);
    uint pos = atomicAdd(&cursor[base + lin], 1u);
    scat[pos] = make_float4(x, y, z, 0.0f);
}

// scan one cell's points against q (fallback / ring path)
__device__ __forceinline__ void scan_cell(
    const uint* __restrict__ starts, const float4* __restrict__ scat,
    int gi, int nTot, float4 q, float& best)
{
    uint s = starts[gi];
    uint e = (gi + 1 < 2 * G3) ? starts[gi + 1] : (uint)nTot;
    for (uint k = s; k < e; ++k) {
        float4 p = scat[k];
        float dx = q.x - p.x, dy = q.y - p.y, dz = q.z - p.z;
        best = fminf(best, dx*dx + dy*dy + dz*dz);
    }
}

// ---- 6: NN query. Block = 16 queries; staged union-box in LDS (shared),
//         block-uniform fallback; rings r<=3; stragglers -> worklist ----
__global__ __launch_bounds__(256) void query_kernel(
    const uint* __restrict__ starts, const float4* __restrict__ scat,
    float* __restrict__ out, uint* __restrict__ wl, uint* __restrict__ wlcount,
    int n1, int n2)
{
    __shared__ float sx[CAP], sy[CAP], sz[CAP];
    __shared__ uint  rOff[NRMAX];       // global span start per staged row
    __shared__ uint  rCum[NRMAX + 1];   // exclusive cumulative staged offsets
    __shared__ int   qc[16][3];
    __shared__ int   sInfo[8];          // X0,X1,Y0,YR,Z0,NR,fbflag,total
    __shared__ float red[4];

    const int nTot  = n1 + n2;          // 32768; % 16 == 0 -> all blocks full
    const int tid   = threadIdx.x;
    const int sub   = tid & 15;
    const int grp   = tid >> 4;
    const int qbase = blockIdx.x * 16;
    const int i     = qbase + grp;

    const int  cb       = (qbase < n1) ? G3 : 0;             // other cloud
    const bool straddle = ((qbase < n1) != (qbase + 15 < n1));

    // ---- union of the 16 query cells (+1 ring), block-shared ----
    if (tid < 16) {
        float4 q = scat[qbase + tid];
        qc[tid][0] = cell1(q.x); qc[tid][1] = cell1(q.y); qc[tid][2] = cell1(q.z);
    }
    __syncthreads();
    if (tid == 0) {
        int x0 = qc[0][0], x1 = x0, y0 = qc[0][1], y1 = y0, z0 = qc[0][2], z1 = z0;
        for (int j = 1; j < 16; ++j) {
            int a = qc[j][0], b = qc[j][1], c = qc[j][2];
            x0 = a < x0 ? a : x0;  x1 = a > x1 ? a : x1;
            y0 = b < y0 ? b : y0;  y1 = b > y1 ? b : y1;
            z0 = c < z0 ? c : z0;  z1 = c > z1 ? c : z1;
        }
        x0 = x0 > 0 ? x0 - 1 : 0;  x1 = x1 < G - 1 ? x1 + 1 : G - 1;
        y0 = y0 > 0 ? y0 - 1 : 0;  y1 = y1 < G - 1 ? y1 + 1 : G - 1;
        z0 = z0 > 0 ? z0 - 1 : 0;  z1 = z1 < G - 1 ? z1 + 1 : G - 1;
        int yr = y1 - y0 + 1, nr = (z1 - z0 + 1) * yr;
        sInfo[0] = x0; sInfo[1] = x1; sInfo[2] = y0; sInfo[3] = yr; sInfo[4] = z0;
        sInfo[5] = nr;
        sInfo[6] = (straddle || nr > NRMAX) ? 1 : 0;
        sInfo[7] = 0;
    }
    __syncthreads();

    const int NR = sInfo[5];
    bool fb = sInfo[6] != 0;

    // ---- row spans (contiguous CSR runs) + wave-0 prefix scan ----
    if (!fb && tid < 64) {
        uint len = 0;
        if (tid < NR) {
            int z = sInfo[4] + tid / sInfo[3];
            int y = sInfo[2] + tid % sInfo[3];
            int rowb = cb + (z * G + y) * G;
            int gi1  = rowb + sInfo[1] + 1;
            uint s = starts[rowb + sInfo[0]];
            uint e = (gi1 < 2 * G3) ? starts[gi1] : (uint)nTot;
            rOff[tid] = s;
            len = e - s;
        }
        uint x = len;
#pragma unroll
        for (int d = 1; d < 64; d <<= 1) { uint t = __shfl_up(x, d); if (tid >= d) x += t; }
        rCum[tid + 1] = x;
        if (tid == 0)  rCum[0] = 0;
        if (tid == 63) sInfo[7] = (int)x;      // total (lanes >= NR added zeros)
    }
    __syncthreads();

    const int total = sInfo[7];
    fb = fb || (total > CAP);                  // block-uniform (LDS-derived)

    // ---- cooperative staged copy (SoA; binary search row by offset) ----
    if (!fb) {
        for (int c = tid; c < total; c += 256) {
            int lo = 0, hi = NR - 1;
            while (lo < hi) { int mid = (lo + hi + 1) >> 1; if ((int)rCum[mid] <= c) lo = mid; else hi = mid - 1; }
            float4 p = scat[rOff[lo] + (uint)(c - (int)rCum[lo])];
            sx[c] = p.x; sy[c] = p.y; sz[c] = p.z;
        }
    }
    __syncthreads();

    // ---- per-query eval ----
    float4 q = scat[i];
    const int cellBase = (i < n1) ? G3 : 0;
    int cx = cell1(q.x), cy = cell1(q.y), cz = cell1(q.z);
    float best = 1e30f;

    if (!fb) {
        // staged union covers each query's full 3x3x3 box (bound intact);
        // extra candidates only lower best (safe).
        for (int c = sub; c < total; c += 16) {
            float dx = q.x - sx[c], dy = q.y - sy[c], dz = q.z - sz[c];
            best = fminf(best, dx*dx + dy*dy + dz*dz);
        }
    } else {
        // fallback: per-query 27-cell box (proven R21/R22 path)
        for (int idx = sub; idx < 27; idx += 16) {
            int dz = idx / 9 - 1, rem = idx % 9;
            int dy = rem / 3 - 1, dx = rem % 3 - 1;
            int x = cx + dx, y = cy + dy, z = cz + dz;
            if ((uint)x >= G || (uint)y >= G || (uint)z >= G) continue;
            scan_cell(starts, scat, cellBase + (z * G + y) * G + x, nTot, q, best);
        }
    }
#pragma unroll
    for (int m = 1; m <= 8; m <<= 1) best = fminf(best, __shfl_xor(best, m, 16));

    // rings 2..3 (rare; tail goes to the brute-force worklist)
    if (best > FH * FH) {
        for (int r = 2; r <= 3; ++r) {
            float bd = (float)(r - 1) * FH;    // unscanned >= (r-1)*h away
            if (best <= bd * bd) break;
            const int S = 2 * r + 1, I = 2 * r - 1;
            const int nf = 2 * S * S, ne = 2 * I * S;
            const int nc = 24 * r * r + 2;
            for (int idx = sub; idx < nc; idx += 16) {
                int dz, dy, dx, t = idx;
                if (t < nf) {
                    int f = t / (S * S); int rem = t - f * S * S;
                    dz = f ? r : -r; dy = rem / S - r; dx = rem - (rem / S) * S - r;
                } else {
                    t -= nf;
                    if (t < ne) {
                        int f = t / (I * S); int rem = t - f * I * S;
                        dy = f ? r : -r; dz = rem / S - (r - 1); dx = rem - (rem / S) * S - r;
                    } else {
                        t -= ne;
                        int f = t / (I * I); int rem = t - f * I * I;
                        dx = f ? r : -r; dz = rem / I - (r - 1); dy = rem - (rem / I) * I - (r - 1);
                    }
                }
                int x = cx + dx, y = cy + dy, z = cz + dz;
                if ((uint)x >= G || (uint)y >= G || (uint)z >= G) continue;
                scan_cell(starts, scat, cellBase + (z * G + y) * G + x, nTot, q, best);
            }
#pragma unroll
            for (int m = 1; m <= 8; m <<= 1) best = fminf(best, __shfl_xor(best, m, 16));
        }
    }

    // exact iff best <= (3h)^2 (rings 0..3 scanned); else brute-force later
    float acc = 0.0f;
    if (best <= 9.0f * FH * FH) {
        if (sub == 0) acc = sqrtf(best);
    } else {
        if (sub == 0) { uint pos = atomicAdd(wlcount, 1u); wl[pos] = (uint)i; }
    }

    // block sum: sub==0 lanes live at wave lanes 0,16,32,48
#pragma unroll
    for (int m = 16; m <= 32; m <<= 1) acc += __shfl_xor(acc, m);
    if ((tid & 63) == 0) red[tid >> 6] = acc;
    __syncthreads();
    if (tid == 0) atomicAdd(out, red[0] + red[1] + red[2] + red[3]);
}

// ---- 7: brute-force the worklist: one block per query, streaming L2 ----
__global__ __launch_bounds__(256) void brute_kernel(
    const float4* __restrict__ scat, const uint* __restrict__ wl,
    const uint* __restrict__ wlcount, float* __restrict__ out, int n1, int n2)
{
    __shared__ float red[4];
    const int nTot = n1 + n2;
    const uint cnt = wlcount[0];
    for (uint w = blockIdx.x; w < cnt; w += gridDim.x) {
        uint qi = wl[w];
        float4 q = scat[qi];
        int ob = (qi < (uint)n1) ? n1 : 0;         // other cloud's scat range
        int oe = (qi < (uint)n1) ? nTot : n1;
        float best = 1e30f;
        for (int j = ob + threadIdx.x; j < oe; j += 256) {
            float4 p = scat[j];
            float dx = q.x - p.x, dy = q.y - p.y, dz = q.z - p.z;
            best = fminf(best, dx*dx + dy*dy + dz*dz);
        }
#pragma unroll
        for (int m = 1; m <= 32; m <<= 1) best = fminf(best, __shfl_xor(best, m));
        if ((threadIdx.x & 63) == 0) red[threadIdx.x >> 6] = best;
        __syncthreads();
        if (threadIdx.x == 0) {
            float b = fminf(fminf(red[0], red[1]), fminf(red[2], red[3]));
            atomicAdd(out, sqrtf(b));
        }
        __syncthreads();                           // red reused next item
    }
}

extern "C" void kernel_launch(void* const* d_in, const int* in_sizes, int n_in,
                              void* d_out, int out_size, void* d_ws, size_t ws_size,
                              hipStream_t stream) {
    const float* P1 = (const float*)d_in[0];
    const float* P2 = (const float*)d_in[1];
    const int n1 = in_sizes[0] / 3;   // 16384
    const int n2 = in_sizes[1] / 3;   // 16384
    const int nTot = n1 + n2;
    const int NB = (2 * G3) / 1024;   // 216 scan blocks

    uint*   counts  = (uint*)d_ws;
    uint*   starts  = counts + 2 * G3;
    uint*   cursor  = starts + 2 * G3;
    uint*   bsums   = cursor + 2 * G3;            // [NB], padded to 1024
    float4* scat    = (float4*)(bsums + 1024);    // 16B-aligned by layout
    uint*   wl      = (uint*)(scat + 32768);
    uint*   wlcount = wl + 32768;
    float*  out     = (float*)d_out;

    hipMemsetAsync(counts, 0, 2 * G3 * sizeof(uint), stream);

    hist_kernel   <<<(nTot + 255) / 256, 256, 0, stream>>>(P1, P2, counts, n1, n2);
    scan1_kernel  <<<NB, 1024, 0, stream>>>(counts, starts, bsums);
    scan2_kernel  <<<1, 256, 0, stream>>>(bsums, NB);
    scan3_kernel  <<<NB, 1024, 0, stream>>>(starts, cursor, bsums, out, wlcount);
    scatter_kernel<<<(nTot + 255) / 256, 256, 0, stream>>>(P1, P2, cursor, scat, n1, n2);
    query_kernel  <<<nTot / 16, 256, 0, stream>>>(starts, scat, out, wl, wlcount, n1, n2);
    brute_kernel  <<<1024, 256, 0, stream>>>(scat, wl, wlcount, out, n1, n2);
}